// Round 9
// baseline (292.378 us; speedup 1.0000x reference)
//
#include <hip/hip_runtime.h>

#define WW 1024
#define HH 1024
#define NIMG 2
#define NCH 8
#define HWSZ (HH * WW)
#define CHW (NCH * HWSZ)
#define NBLK_MASK 2048
#define NBLK_MAIN 2048
// ws u32 layout: [0..2047] block mins, [2048..4095] block maxs,
// [4096] sum, [4097] cnt, [4098] ticket,
// dv16 (packed unorm16 mask diff) at 4352, u8 qt records at WS_QT.
#define WS_SUM 4096
#define WS_CNT 4097
#define WS_TKT 4098
#define WS_DV16 4352
#define WS_QT (4352 + HWSZ)
#define RECU4 320   // uint4 per (n,row,half) record: [p0 136][p1 136][pad 48]
#define SLOTU 1280  // u32 per LDS slot (= record size)

typedef unsigned int uint;

__device__ __forceinline__ uint pknorm(float a, float b) {
    uint d;
    asm("v_cvt_pknorm_u16_f32 %0, %1, %2" : "=v"(d) : "v"(a), "v"(b));
    return d;
}
__device__ __forceinline__ uint sadu8(uint a, uint b, uint c) {
    uint d;
    asm("v_sad_u8 %0, %1, %2, %3" : "=v"(d) : "v"(a), "v"(b), "v"(c));
    return d;
}
__device__ __forceinline__ uint q8(float x) {
    return (uint)__float2int_rn(x * 255.f);
}
__device__ __forceinline__ int reflect_idx(int t) {
    if (t < 0) t = -t;
    if (t > HH - 1) t = 2 * (HH - 1) - t;
    return t;
}
__device__ __forceinline__ int gp2slot(int gp) {
    return (gp & 1) ? (68 + (gp >> 1)) : (gp >> 1);
}

#define GLD16(g, l)                                                         \
    __builtin_amdgcn_global_load_lds(                                       \
        (const __attribute__((address_space(1))) uint*)(g),                 \
        (__attribute__((address_space(3))) uint*)(l), 16, 0, 0)

// Pass 0: quantize tgt to u8 (4 ch per u32); per (n,row,half) a 320-uint4 record
// [p0: E68|O68][p1: E68|O68][pad], reflected col-halos baked in. (verified R8)
__global__ __launch_bounds__(256) void k_quant(const float* __restrict__ tgt,
                                               uint4* __restrict__ qt4) {
    int b = blockIdx.x;            // (n*2+p)*1024 + row
    int t = threadIdx.x;
    int row = b & 1023;
    int np = b >> 10;
    int n = np >> 1, p = np & 1;
    const float* c0 = tgt + (size_t)(n * NCH + 4 * p) * HWSZ + (size_t)row * WW;

    float4 v0 = *(const float4*)(c0 + 4 * t);
    float4 v1 = *(const float4*)(c0 + HWSZ + 4 * t);
    float4 v2 = *(const float4*)(c0 + 2 * HWSZ + 4 * t);
    float4 v3 = *(const float4*)(c0 + 3 * HWSZ + 4 * t);
    uint4 u;
    u.x = q8(v0.x) | (q8(v1.x) << 8) | (q8(v2.x) << 16) | (q8(v3.x) << 24);
    u.y = q8(v0.y) | (q8(v1.y) << 8) | (q8(v2.y) << 16) | (q8(v3.y) << 24);
    u.z = q8(v0.z) | (q8(v1.z) << 8) | (q8(v2.z) << 16) | (q8(v3.z) << 24);
    u.w = q8(v0.w) | (q8(v1.w) << 8) | (q8(v2.w) << 16) | (q8(v3.w) << 24);

    size_t rb = ((size_t)((n << 10) + row)) * 2;
    int h1 = t >> 7;
    int gp = (t & 127) + 4;
    qt4[(rb + h1) * RECU4 + p * 136 + gp2slot(gp)] = u;
    if (t >= 124 && t < 128)
        qt4[(rb + 1) * RECU4 + p * 136 + gp2slot(t - 124)] = u;
    if (t >= 128 && t < 132)
        qt4[(rb + 0) * RECU4 + p * 136 + gp2slot(t - 128 + 132)] = u;
    if (t < 32) {
        int which = t >> 4, m = t & 15;
        int pc = which ? (528 + m) : m;
        int j = which ? (1022 - m) : (16 - m);
        uint val = q8(c0[j]) | (q8(c0[j + HWSZ]) << 8) |
                   (q8(c0[j + 2 * HWSZ]) << 16) | (q8(c0[j + 3 * HWSZ]) << 24);
        uint* recU = (uint*)(qt4 + (rb + which) * RECU4);
        recU[p * 544 + gp2slot(pc >> 2) * 4 + (pc & 3)] = val;
    }
}

// Pass 1: mask diff -> packed unorm16; per-block min/max. (verified, unchanged)
__global__ __launch_bounds__(256) void k_mask(const float* __restrict__ msO,
                                              const float* __restrict__ pan,
                                              float* __restrict__ wsF,
                                              uint* __restrict__ dv16) {
    int b = blockIdx.x;
    int gid = b * 256 + threadIdx.x;
    int base = gid * 4;
    int n = base >> 20;
    int hw = base & (HWSZ - 1);
    const float* po = msO + (size_t)n * CHW + hw;
    float sx = 0.f, sy = 0.f, sz = 0.f, sw = 0.f;
#pragma unroll
    for (int c = 0; c < NCH; ++c) {
        float4 v = *(const float4*)(po + c * HWSZ);
        sx += v.x; sy += v.y; sz += v.z; sw += v.w;
    }
    float4 pv = *(const float4*)(pan + (size_t)n * HWSZ + hw);
    float4 d;
    d.x = fabsf(sx * 0.125f - pv.x);
    d.y = fabsf(sy * 0.125f - pv.y);
    d.z = fabsf(sz * 0.125f - pv.z);
    d.w = fabsf(sw * 0.125f - pv.w);
    uint2 dpk;
    dpk.x = pknorm(d.x, d.y);
    dpk.y = pknorm(d.z, d.w);
    *(uint2*)(dv16 + (base >> 1)) = dpk;

    float m = fminf(fminf(d.x, d.y), fminf(d.z, d.w));
    float M = fmaxf(fmaxf(d.x, d.y), fmaxf(d.z, d.w));
#pragma unroll
    for (int off = 32; off > 0; off >>= 1) {
        m = fminf(m, __shfl_down(m, off));
        M = fmaxf(M, __shfl_down(M, off));
    }
    __shared__ float sm[4], sM[4];
    int wid = threadIdx.x >> 6, lane = threadIdx.x & 63;
    if (lane == 0) { sm[wid] = m; sM[wid] = M; }
    __syncthreads();
    if (threadIdx.x == 0) {
        wsF[b] = fminf(fminf(sm[0], sm[1]), fminf(sm[2], sm[3]));
        wsF[2048 + b] = fmaxf(fmaxf(sM[0], sM[1]), fmaxf(sM[2], sM[3]));
        if (b == 0) {
            wsF[WS_SUM] = 0.f;
            wsF[WS_CNT] = 0.f;
            ((unsigned*)wsF)[WS_TKT] = 0u;
        }
    }
}

// Pass 2: 1-wave block = half-row pair (output rows h0, h0+4). Stage-outer loop:
// each of 10 target rows staged ONCE into a 2-slot (10 KB) double buffer via DMA;
// per stage, window regs read once and swept for both output rows.
__global__ __launch_bounds__(64) void k_main(const float* __restrict__ ms,
                                             const uint4* __restrict__ qt4,
                                             float* __restrict__ wsF,
                                             const uint* __restrict__ dv16,
                                             float* __restrict__ out) {
    __shared__ __align__(16) uint ldsU[2 * SLOTU]; // 10 KB
    const int t = threadIdx.x;        // 0..63
    const int b = blockIdx.x;         // 0..2047
    const int xcd = b & 7;
    const int q = b >> 3;             // 0..255
    const int n = q >> 7;
    const int r = q & 127;
    const int hb = r >> 6;
    const int w = r & 63;
    const int h0 = xcd * 128 + 8 * (w >> 2) + (w & 3); // rows h0 and h0+4
    const int w0 = hb * 512 + 8 * t;

    // mask min/max loads (issued first; drained during shuffle reduce)
    float lmin = 1.0e38f, lmax = -1.0e38f;
#pragma unroll
    for (int k = 0; k < 8; ++k) {
        float4 v = ((const float4*)wsF)[k * 64 + t];
        float4 x = ((const float4*)(wsF + 2048))[k * 64 + t];
        lmin = fminf(lmin, fminf(fminf(v.x, v.y), fminf(v.z, v.w)));
        lmax = fmaxf(lmax, fmaxf(fmaxf(x.x, x.y), fmaxf(x.z, x.w)));
    }

    const size_t nBase = ((size_t)n << 10);
    // stage row s (s in 0..9, image row h0+4*(s-4)) into slot
#define STAGE(s, slot)                                                      \
    do {                                                                    \
        int row_ = reflect_idx(h0 + 4 * ((s) - 4));                         \
        const uint* rec_ = (const uint*)(qt4 + ((nBase + row_) * 2 + hb) * RECU4); \
        _Pragma("unroll")                                                   \
        for (int c_ = 0; c_ < 5; ++c_)                                      \
            GLD16(rec_ + c_ * 256 + 4 * t, &ldsU[(slot) * SLOTU + c_ * 256]); \
    } while (0)

    STAGE(0, 0);

    // ms fragments for both rows (loads drain DMA(0) too — harmless)
    uint msq[2][2][8]; // [k][plane][px]
#pragma unroll
    for (int k = 0; k < 2; ++k) {
        const float* msBase = ms + (size_t)n * CHW + (size_t)(h0 + 4 * k) * WW + w0;
#pragma unroll
        for (int p = 0; p < 2; ++p) {
            float4 c0a = *(const float4*)(msBase + (size_t)(4 * p + 0) * HWSZ);
            float4 c0b = *(const float4*)(msBase + (size_t)(4 * p + 0) * HWSZ + 4);
            float4 c1a = *(const float4*)(msBase + (size_t)(4 * p + 1) * HWSZ);
            float4 c1b = *(const float4*)(msBase + (size_t)(4 * p + 1) * HWSZ + 4);
            float4 c2a = *(const float4*)(msBase + (size_t)(4 * p + 2) * HWSZ);
            float4 c2b = *(const float4*)(msBase + (size_t)(4 * p + 2) * HWSZ + 4);
            float4 c3a = *(const float4*)(msBase + (size_t)(4 * p + 3) * HWSZ);
            float4 c3b = *(const float4*)(msBase + (size_t)(4 * p + 3) * HWSZ + 4);
            msq[k][p][0] = q8(c0a.x) | (q8(c1a.x) << 8) | (q8(c2a.x) << 16) | (q8(c3a.x) << 24);
            msq[k][p][1] = q8(c0a.y) | (q8(c1a.y) << 8) | (q8(c2a.y) << 16) | (q8(c3a.y) << 24);
            msq[k][p][2] = q8(c0a.z) | (q8(c1a.z) << 8) | (q8(c2a.z) << 16) | (q8(c3a.z) << 24);
            msq[k][p][3] = q8(c0a.w) | (q8(c1a.w) << 8) | (q8(c2a.w) << 16) | (q8(c3a.w) << 24);
            msq[k][p][4] = q8(c0b.x) | (q8(c1b.x) << 8) | (q8(c2b.x) << 16) | (q8(c3b.x) << 24);
            msq[k][p][5] = q8(c0b.y) | (q8(c1b.y) << 8) | (q8(c2b.y) << 16) | (q8(c3b.y) << 24);
            msq[k][p][6] = q8(c0b.z) | (q8(c1b.z) << 8) | (q8(c2b.z) << 16) | (q8(c3b.z) << 24);
            msq[k][p][7] = q8(c0b.w) | (q8(c1b.w) << 8) | (q8(c2b.w) << 16) | (q8(c3b.w) << 24);
        }
    }
    uint4 dq[2];
#pragma unroll
    for (int k = 0; k < 2; ++k)
        dq[k] = *(const uint4*)(dv16 +
            (((size_t)n * HWSZ + (size_t)(h0 + 4 * k) * WW + w0) >> 1));

#pragma unroll
    for (int off = 32; off > 0; off >>= 1) {
        lmin = fminf(lmin, __shfl_xor(lmin, off));
        lmax = fmaxf(lmax, __shfl_xor(lmax, off));
    }
    const float thresh = lmin + (lmax - lmin) * (10.0f / 255.0f);

    uint minv[2][8];
#pragma unroll
    for (int k = 0; k < 2; ++k)
#pragma unroll
        for (int p = 0; p < 8; ++p) minv[k][p] = 0xffffffffu;

#pragma unroll 1
    for (int s = 0; s < 10; ++s) {
        if (s < 9) {
            STAGE(s + 1, (s + 1) & 1);
            asm volatile("s_waitcnt vmcnt(5)" ::: "memory"); // DMA(s) complete
        } else {
            asm volatile("s_waitcnt vmcnt(0)" ::: "memory");
        }
        const uint* sb = &ldsU[(s & 1) * SLOTU];
        // 40-px windows, read once per stage, reused for both output rows
        uint4 winE[2][5], winO[2][5];
#pragma unroll
        for (int p = 0; p < 2; ++p)
#pragma unroll
            for (int qq = 0; qq < 5; ++qq) {
                winE[p][qq] = *(const uint4*)(sb + p * 544 + 4 * (t + qq));
                winO[p][qq] = *(const uint4*)(sb + p * 544 + 272 + 4 * (t + qq));
            }
#pragma unroll
        for (int k = 0; k < 2; ++k) {
            if (s < k || s - k > 8) continue; // di = s-k out of range
            uint acc[8];
#pragma unroll
            for (int dj = 0; dj < 9; ++dj) {
#pragma unroll
                for (int p = 0; p < 8; ++p) acc[p] = 0;
#pragma unroll
                for (int p = 0; p < 2; ++p) {
                    uint4 lo = (dj & 1) ? winO[p][(dj - 1) >> 1] : winE[p][dj >> 1];
                    uint4 hi = (dj & 1) ? winE[p][(dj + 1) >> 1] : winO[p][dj >> 1];
                    acc[0] = sadu8(msq[k][p][0], lo.x, acc[0]);
                    acc[1] = sadu8(msq[k][p][1], lo.y, acc[1]);
                    acc[2] = sadu8(msq[k][p][2], lo.z, acc[2]);
                    acc[3] = sadu8(msq[k][p][3], lo.w, acc[3]);
                    acc[4] = sadu8(msq[k][p][4], hi.x, acc[4]);
                    acc[5] = sadu8(msq[k][p][5], hi.y, acc[5]);
                    acc[6] = sadu8(msq[k][p][6], hi.z, acc[6]);
                    acc[7] = sadu8(msq[k][p][7], hi.w, acc[7]);
                }
#pragma unroll
                for (int p = 0; p < 8; ++p) minv[k][p] = min(minv[k][p], acc[p]);
            }
        }
    }

    // epilogue: masked accumulate for both rows
    const float inv16 = 1.0f / 65535.0f;
    const float inv8 = 1.0f / 255.0f;
    float lsum = 0.f, lcnt = 0.f;
#pragma unroll
    for (int k = 0; k < 2; ++k) {
        uint dw[4] = {dq[k].x, dq[k].y, dq[k].z, dq[k].w};
#pragma unroll
        for (int p = 0; p < 4; ++p) {
            float d0 = (float)(dw[p] & 0xffffu) * inv16;
            float d1 = (float)(dw[p] >> 16) * inv16;
            if (d0 > thresh) { lsum += (float)minv[k][2 * p] * inv8; lcnt += 1.f; }
            if (d1 > thresh) { lsum += (float)minv[k][2 * p + 1] * inv8; lcnt += 1.f; }
        }
    }
#pragma unroll
    for (int off = 32; off > 0; off >>= 1) {
        lsum += __shfl_down(lsum, off);
        lcnt += __shfl_down(lcnt, off);
    }
    if (t == 0) {
        atomicAdd(&wsF[WS_SUM], lsum);
        atomicAdd(&wsF[WS_CNT], lcnt);
        __threadfence();
        unsigned tk = atomicAdd((unsigned*)&wsF[WS_TKT], 1u);
        if (tk == NBLK_MAIN - 1) {
            float s = atomicAdd(&wsF[WS_SUM], 0.f);
            float c = atomicAdd(&wsF[WS_CNT], 0.f);
            out[0] = (c > 0.f) ? (s / fmaxf(c, 1.f)) : 0.f;
        }
    }
#undef STAGE
}

extern "C" void kernel_launch(void* const* d_in, const int* in_sizes, int n_in,
                              void* d_out, int out_size, void* d_ws, size_t ws_size,
                              hipStream_t stream) {
    const float* ms  = (const float*)d_in[0];
    const float* tgt = (const float*)d_in[1];
    const float* msO = (const float*)d_in[2];
    const float* pan = (const float*)d_in[3];
    float* out = (float*)d_out;
    float* wsF = (float*)d_ws;
    uint* dv16 = (uint*)d_ws + WS_DV16;
    uint4* qt4 = (uint4*)((uint*)d_ws + WS_QT);

    k_quant<<<NIMG * 2 * 1024, 256, 0, stream>>>(tgt, qt4);
    k_mask<<<NBLK_MASK, 256, 0, stream>>>(msO, pan, wsF, dv16);
    k_main<<<NBLK_MAIN, 64, 0, stream>>>(ms, qt4, wsF, dv16, out);
}